// Round 1
// 368.376 us; speedup vs baseline: 1.0271x; 1.0271x over previous
//
#include <hip/hip_runtime.h>
#include <hip/hip_bf16.h>

#define N_FILT   80
#define FILT_DIM 251
#define PAD      125
#define SEQ      32000
#define BATCH    32
#define TWO_PI_F 6.28318530717958647692f

typedef __attribute__((ext_vector_type(8))) short short8;
typedef __attribute__((ext_vector_type(4))) float floatx4;

// ---------------- Kernel 1: filters -> bf16 fragments (UNCHANGED) ----------
// Fragment order works for BOTH operand roles: lane&15 indexes the non-K dim,
// (lane>>4)*8+j indexes K.  half-index: (((ft*8+ks)*4+q)*16 + m)*8 + j,
// f = 16*ft + m, tap k = 32*ks + 8*q + j.  K padded 251->256 with zeros.
__global__ void gen_filters(const float* __restrict__ b1p,
                            const float* __restrict__ bandp,
                            unsigned short* __restrict__ afrag) {
    const int f = blockIdx.x;      // filter 0..79
    const int i = threadIdx.x;     // tap 0..255

    const float min_f = 0.003125f; // 50/16000 exact
    float b1   = fabsf(b1p[f]);
    float band = fabsf(bandp[f]);
    float beg  = b1 + min_f;
    float end  = beg + band + min_f;

    float bp = -1e30f;
    if (i < FILT_DIM) {
        int d = i - PAD;
        float lpe, lpb;
        if (d == 0) { lpe = 2.0f*end; lpb = 2.0f*beg; }
        else {
            float kf = (float)(d < 0 ? -d : d);
            float ae = (TWO_PI_F * (end * 16000.0f)) * kf;
            float ab = (TWO_PI_F * (beg * 16000.0f)) * kf;
            lpe = (2.0f*end) * (sinf(ae)/ae);
            lpb = (2.0f*beg) * (sinf(ab)/ab);
        }
        bp = lpe - lpb;
    }

    __shared__ float red[256];
    red[i] = bp;
    __syncthreads();
    for (int s = 128; s > 0; s >>= 1) {
        if (i < s) red[i] = fmaxf(red[i], red[i+s]);
        __syncthreads();
    }
    float mx = red[0];

    float val = 0.0f;
    if (i < FILT_DIM) {
        float n = (float)i * (251.0f/250.0f);
        float w = 0.54f - 0.46f*cosf((TWO_PI_F*n)/251.0f);
        val = (bp/mx) * w;
    }
    __hip_bfloat16 h = __float2bfloat16(val);
    const int ft = f >> 4, m = f & 15;
    const int ks = i >> 5, q = (i >> 3) & 3, j = i & 7;
    afrag[((((ft*8+ks)*4+q)*16) + m)*8 + j] = *reinterpret_cast<unsigned short*>(&h);
}

// ---------------- Kernel 2: implicit-GEMM conv, SWAPPED operands -----------
// A = x (rows = positions), B = filters (cols = filters), held in REGISTERS.
// D rows = positions -> each lane owns 4 consecutive positions of one filter
// -> float4 stores.  8 shifted bf16 x-copies keep A-frag loads as aligned
// conflict-free ds_read_b128:
//   A[m][k] = x[t0 + pt*16 + m - 125 + k],  m = lane&15, k = 8*q + j + 32*ks
//   copy c = m&7 = lane&7;  i = pt*16 + 8*(m>>3) + 8*q + 32*ks  (mult of 8)
#define BLK_POS 1280
#define NPT     (BLK_POS/16)   // 80 pos-tiles
#define PT_W    (NPT/4)        // 20 per wave
#define XS_LEN  1528           // staged halfwords per copy (max i+7 = 1527)
#define XS_H    1544           // stride: 772 dwords == 4 (mod 32) -> +4-bank phase/copy

__global__ __launch_bounds__(256, 2) void conv_mfma(
        const float* __restrict__ x,
        const unsigned short* __restrict__ afrag,
        float* __restrict__ out) {
    __shared__ __align__(16) unsigned short xsh[8*XS_H];   // 24704 B

    const int b    = blockIdx.y;
    const int t0   = blockIdx.x * BLK_POS;
    const int tid  = threadIdx.x;
    const int lane = tid & 63;
    const int w    = tid >> 6;
    const int n    = lane & 15;    // MFMA col = filter within ftile
    const int q    = lane >> 4;    // quad -> k-base 8q, D-rows 4q..4q+3
    const float* xb = x + (size_t)b * SEQ;

    // filter B-fragments -> registers (40 x 16B per lane, L2-resident)
    short8 F[5][8];
    #pragma unroll
    for (int ft = 0; ft < 5; ++ft)
        #pragma unroll
        for (int ks = 0; ks < 8; ++ks)
            F[ft][ks] = *reinterpret_cast<const short8*>(
                afrag + ((((ft*8+ks)*4+q)*16) + n)*8);

    // x tile -> 8 shifted bf16 copies (zero-padded outside the sequence)
    for (int c = 0; c < 8; ++c) {
        unsigned short* cp = xsh + c*XS_H;
        for (int m = tid; m < XS_LEN; m += 256) {
            int g = t0 - PAD + m + c;
            float v = (g >= 0 && g < SEQ) ? xb[g] : 0.0f;
            __hip_bfloat16 h = __float2bfloat16(v);
            cp[m] = *reinterpret_cast<unsigned short*>(&h);
        }
    }
    __syncthreads();

    // per-lane A-frag base: copy (lane&7), + 8*bit3(m) + 8*q halfwords
    const int abase = (lane & 7)*XS_H + 8*((lane >> 3) & 1) + 8*q;
    // per-lane output base: filter n, position t0 + 4q (+ pt*16 + ft*16*SEQ)
    float* ob = out + ((size_t)b*N_FILT + n)*SEQ + t0 + 4*q;

    for (int t = 0; t < PT_W; ++t) {
        const int pt = w*PT_W + t;
        short8 A[8];
        #pragma unroll
        for (int ks = 0; ks < 8; ++ks)
            A[ks] = *reinterpret_cast<const short8*>(
                xsh + abase + pt*16 + 32*ks);
        #pragma unroll
        for (int ft = 0; ft < 5; ++ft) {
            floatx4 acc = {0.f, 0.f, 0.f, 0.f};
            #pragma unroll
            for (int ks = 0; ks < 8; ++ks)
                acc = __builtin_amdgcn_mfma_f32_16x16x32_bf16(
                          A[ks], F[ft][ks], acc, 0, 0, 0);
            // D: col = lane&15 (filter), row = 4q + r (position) -> float4
            *reinterpret_cast<floatx4*>(ob + (size_t)(ft*16)*SEQ + pt*16) = acc;
        }
    }
}

extern "C" void kernel_launch(void* const* d_in, const int* in_sizes, int n_in,
                              void* d_out, int out_size, void* d_ws, size_t ws_size,
                              hipStream_t stream) {
    const float* x    = (const float*)d_in[0];
    const float* b1   = (const float*)d_in[1];
    const float* band = (const float*)d_in[2];
    unsigned short* afrag = (unsigned short*)d_ws;   // 80*256*2 = 40960 B
    float* out = (float*)d_out;

    gen_filters<<<N_FILT, 256, 0, stream>>>(b1, band, afrag);

    dim3 grid(SEQ / BLK_POS, BATCH);                 // 25 x 32 = 800 blocks
    conv_mfma<<<grid, 256, 0, stream>>>(x, afrag, out);
}

// Round 2
// 359.242 us; speedup vs baseline: 1.0532x; 1.0254x over previous
//
#include <hip/hip_runtime.h>
#include <hip/hip_bf16.h>

#define N_FILT   80
#define FILT_DIM 251
#define PAD      125
#define SEQ      32000
#define BATCH    32
#define TWO_PI_F 6.28318530717958647692f

typedef __attribute__((ext_vector_type(8))) short short8;
typedef __attribute__((ext_vector_type(4))) float floatx4;

// ---------------- Kernel 1: filters -> bf16 fragments (UNCHANGED) ----------
// Fragment order works for BOTH operand roles: lane&15 indexes the non-K dim,
// (lane>>4)*8+j indexes K.  half-index: (((ft*8+ks)*4+q)*16 + m)*8 + j,
// f = 16*ft + m, tap k = 32*ks + 8*q + j.  K padded 251->256 with zeros.
__global__ void gen_filters(const float* __restrict__ b1p,
                            const float* __restrict__ bandp,
                            unsigned short* __restrict__ afrag) {
    const int f = blockIdx.x;      // filter 0..79
    const int i = threadIdx.x;     // tap 0..255

    const float min_f = 0.003125f; // 50/16000 exact
    float b1   = fabsf(b1p[f]);
    float band = fabsf(bandp[f]);
    float beg  = b1 + min_f;
    float end  = beg + band + min_f;

    float bp = -1e30f;
    if (i < FILT_DIM) {
        int d = i - PAD;
        float lpe, lpb;
        if (d == 0) { lpe = 2.0f*end; lpb = 2.0f*beg; }
        else {
            float kf = (float)(d < 0 ? -d : d);
            float ae = (TWO_PI_F * (end * 16000.0f)) * kf;
            float ab = (TWO_PI_F * (beg * 16000.0f)) * kf;
            lpe = (2.0f*end) * (sinf(ae)/ae);
            lpb = (2.0f*beg) * (sinf(ab)/ab);
        }
        bp = lpe - lpb;
    }

    __shared__ float red[256];
    red[i] = bp;
    __syncthreads();
    for (int s = 128; s > 0; s >>= 1) {
        if (i < s) red[i] = fmaxf(red[i], red[i+s]);
        __syncthreads();
    }
    float mx = red[0];

    float val = 0.0f;
    if (i < FILT_DIM) {
        float n = (float)i * (251.0f/250.0f);
        float w = 0.54f - 0.46f*cosf((TWO_PI_F*n)/251.0f);
        val = (bp/mx) * w;
    }
    __hip_bfloat16 h = __float2bfloat16(val);
    const int ft = f >> 4, m = f & 15;
    const int ks = i >> 5, q = (i >> 3) & 3, j = i & 7;
    afrag[((((ft*8+ks)*4+q)*16) + m)*8 + j] = *reinterpret_cast<unsigned short*>(&h);
}

// ---------------- Kernel 2: implicit-GEMM conv, transposed epilogue --------
// A = x (rows = positions), B = filters (regs).  pt = 4t + w so each t-step
// the 4 waves jointly produce a contiguous 64-pos x 80-filt stripe.  The
// stripe is transposed through a double-buffered LDS tile so global stores
// are block-cooperative: each wave store = 4 x 256 B contiguous runs, and
// consecutive t extend each filter row sequentially (L2-mergeable bursts).
#define BLK_POS  1280
#define NT_STEPS 20            // t-steps, 4 pos-tiles (waves) per step
#define XS_LEN   1528          // staged halfwords per copy
#define XS_H     1544          // stride: 772 dw == 4 (mod 32) -> bank phase
#define OS_W     72            // stripe row stride (floats): 8f-mod-32 phase

__global__ __launch_bounds__(256, 2) void conv_mfma(
        const float* __restrict__ x,
        const unsigned short* __restrict__ afrag,
        float* __restrict__ out) {
    __shared__ __align__(16) unsigned short xsh[8*XS_H];        // 24704 B
    __shared__ __align__(16) float osh[2][N_FILT*OS_W];         // 46080 B

    const int b    = blockIdx.y;
    const int t0   = blockIdx.x * BLK_POS;
    const int tid  = threadIdx.x;
    const int lane = tid & 63;
    const int w    = tid >> 6;
    const int n    = lane & 15;    // MFMA col = filter within ftile
    const int q    = lane >> 4;    // quad -> k-base 8q, D-rows 4q..4q+3
    const float* xb = x + (size_t)b * SEQ;

    // filter B-fragments -> registers (40 x 16B per lane, L2-resident)
    short8 F[5][8];
    #pragma unroll
    for (int ft = 0; ft < 5; ++ft)
        #pragma unroll
        for (int ks = 0; ks < 8; ++ks)
            F[ft][ks] = *reinterpret_cast<const short8*>(
                afrag + ((((ft*8+ks)*4+q)*16) + n)*8);

    // x tile -> 8 shifted bf16 copies (zero-padded outside the sequence)
    for (int c = 0; c < 8; ++c) {
        unsigned short* cp = xsh + c*XS_H;
        for (int m = tid; m < XS_LEN; m += 256) {
            int g = t0 - PAD + m + c;
            float v = (g >= 0 && g < SEQ) ? xb[g] : 0.0f;
            __hip_bfloat16 h = __float2bfloat16(v);
            cp[m] = *reinterpret_cast<unsigned short*>(&h);
        }
    }
    __syncthreads();

    // per-lane A-frag base: copy (lane&7), + 8*bit3(m) + 8*q halfwords
    const int abase = (lane & 7)*XS_H + 8*((lane >> 3) & 1) + 8*q;
    float* ob = out + (size_t)b*N_FILT*SEQ + t0;

    for (int t = 0; t < NT_STEPS; ++t) {
        const int pt = 4*t + w;            // wave's pos-tile in this stripe
        short8 A[8];
        #pragma unroll
        for (int ks = 0; ks < 8; ++ks)
            A[ks] = *reinterpret_cast<const short8*>(
                xsh + abase + pt*16 + 32*ks);

        float* buf = osh[t & 1];
        #pragma unroll
        for (int ft = 0; ft < 5; ++ft) {
            floatx4 acc = {0.f, 0.f, 0.f, 0.f};
            #pragma unroll
            for (int ks = 0; ks < 8; ++ks)
                acc = __builtin_amdgcn_mfma_f32_16x16x32_bf16(
                          A[ks], F[ft][ks], acc, 0, 0, 0);
            // D: col = lane&15 (filter), rows = 4q..4q+3 (pos) -> one float4
            // stripe offset = pt*16 - 64t + 4q = 16w + 4q
            *reinterpret_cast<floatx4*>(
                buf + (ft*16 + n)*OS_W + 16*w + 4*q) = acc;
        }
        __syncthreads();   // stripe complete (also fences buf reuse, see note)

        // cooperative store: 80 rows x 64 pos; wave instr = 4 x 256 B runs
        const float* rbuf = osh[t & 1];
        #pragma unroll
        for (int it = 0; it < 5; ++it) {
            int idx = it*256 + tid;
            int f   = idx >> 4;            // filter row 0..79
            int c4  = idx & 15;            // float4 within stripe row
            floatx4 v = *reinterpret_cast<const floatx4*>(
                rbuf + f*OS_W + 4*c4);
            *reinterpret_cast<floatx4*>(
                ob + (size_t)f*SEQ + 64*t + 4*c4) = v;
        }
        // no second barrier: write(t+2) to this buffer happens after
        // bar(t+1), by which time every wave's read(t) is lgkm-drained.
    }
}

extern "C" void kernel_launch(void* const* d_in, const int* in_sizes, int n_in,
                              void* d_out, int out_size, void* d_ws, size_t ws_size,
                              hipStream_t stream) {
    const float* x    = (const float*)d_in[0];
    const float* b1   = (const float*)d_in[1];
    const float* band = (const float*)d_in[2];
    unsigned short* afrag = (unsigned short*)d_ws;   // 80*256*2 = 40960 B
    float* out = (float*)d_out;

    gen_filters<<<N_FILT, 256, 0, stream>>>(b1, band, afrag);

    dim3 grid(SEQ / BLK_POS, BATCH);                 // 25 x 32 = 800 blocks
    conv_mfma<<<grid, 256, 0, stream>>>(x, afrag, out);
}

// Round 3
// 358.033 us; speedup vs baseline: 1.0567x; 1.0034x over previous
//
#include <hip/hip_runtime.h>
#include <hip/hip_bf16.h>

#define N_FILT   80
#define FILT_DIM 251
#define PAD      125
#define SEQ      32000
#define BATCH    32
#define TWO_PI_F 6.28318530717958647692f

typedef __attribute__((ext_vector_type(8))) short short8;
typedef __attribute__((ext_vector_type(4))) float floatx4;

// ---------------- Kernel 1: filters -> bf16 fragments (UNCHANGED) ----------
// Fragment order works for BOTH operand roles: lane&15 indexes the non-K dim,
// (lane>>4)*8+j indexes K.  half-index: (((ft*8+ks)*4+q)*16 + m)*8 + j,
// f = 16*ft + m, tap k = 32*ks + 8*q + j.  K padded 251->256 with zeros.
__global__ void gen_filters(const float* __restrict__ b1p,
                            const float* __restrict__ bandp,
                            unsigned short* __restrict__ afrag) {
    const int f = blockIdx.x;      // filter 0..79
    const int i = threadIdx.x;     // tap 0..255

    const float min_f = 0.003125f; // 50/16000 exact
    float b1   = fabsf(b1p[f]);
    float band = fabsf(bandp[f]);
    float beg  = b1 + min_f;
    float end  = beg + band + min_f;

    float bp = -1e30f;
    if (i < FILT_DIM) {
        int d = i - PAD;
        float lpe, lpb;
        if (d == 0) { lpe = 2.0f*end; lpb = 2.0f*beg; }
        else {
            float kf = (float)(d < 0 ? -d : d);
            float ae = (TWO_PI_F * (end * 16000.0f)) * kf;
            float ab = (TWO_PI_F * (beg * 16000.0f)) * kf;
            lpe = (2.0f*end) * (sinf(ae)/ae);
            lpb = (2.0f*beg) * (sinf(ab)/ab);
        }
        bp = lpe - lpb;
    }

    __shared__ float red[256];
    red[i] = bp;
    __syncthreads();
    for (int s = 128; s > 0; s >>= 1) {
        if (i < s) red[i] = fmaxf(red[i], red[i+s]);
        __syncthreads();
    }
    float mx = red[0];

    float val = 0.0f;
    if (i < FILT_DIM) {
        float n = (float)i * (251.0f/250.0f);
        float w = 0.54f - 0.46f*cosf((TWO_PI_F*n)/251.0f);
        val = (bp/mx) * w;
    }
    __hip_bfloat16 h = __float2bfloat16(val);
    const int ft = f >> 4, m = f & 15;
    const int ks = i >> 5, q = (i >> 3) & 3, j = i & 7;
    afrag[((((ft*8+ks)*4+q)*16) + m)*8 + j] = *reinterpret_cast<unsigned short*>(&h);
}

// ---------------- Kernel 2: implicit-GEMM conv, transposed epilogue --------
// A = x (rows = positions), B = filters (regs).  pt = 4t + w so each t-step
// the 4 waves jointly produce a contiguous 64-pos x 80-filt stripe, which is
// transposed through double-buffered LDS and stored block-cooperatively.
//
// KEY CHANGE (r3): the per-step barrier is a raw s_barrier preceded only by
// s_waitcnt lgkmcnt(0).  __syncthreads() would emit s_waitcnt vmcnt(0) before
// s_barrier, force-draining ALL outstanding global stores once per t-step --
// chopping the write stream into synchronous 20KB bursts with an empty MC
// queue between them (the measured ~137us conv residual vs a ~55us write
// floor).  The osh double-buffer only needs LDS ordering: reads of buf(t) are
// lgkm-complete before barrier(t+1), and writes to the same buffer happen
// after barrier(t+1).  Store-source VGPR reuse is protected by the compiler's
// own counted vmcnt(N) waits, so stores stay deep in flight across steps.
#define BLK_POS  1280
#define NT_STEPS 20            // t-steps, 4 pos-tiles (waves) per step
#define XS_LEN   1528          // staged halfwords per copy
#define XS_H     1544          // stride: 772 dw == 4 (mod 32) -> bank phase
#define OS_W     72            // stripe row stride (floats): 8f-mod-32 phase

__device__ __forceinline__ void barrier_lds_only() {
    asm volatile("s_waitcnt lgkmcnt(0)" ::: "memory");
    __builtin_amdgcn_s_barrier();
}

__global__ __launch_bounds__(256, 2) void conv_mfma(
        const float* __restrict__ x,
        const unsigned short* __restrict__ afrag,
        float* __restrict__ out) {
    __shared__ __align__(16) unsigned short xsh[8*XS_H];        // 24704 B
    __shared__ __align__(16) float osh[2][N_FILT*OS_W];         // 46080 B

    const int b    = blockIdx.y;
    const int t0   = blockIdx.x * BLK_POS;
    const int tid  = threadIdx.x;
    const int lane = tid & 63;
    const int w    = tid >> 6;
    const int n    = lane & 15;    // MFMA col = filter within ftile
    const int q    = lane >> 4;    // quad -> k-base 8q, D-rows 4q..4q+3
    const float* xb = x + (size_t)b * SEQ;

    // filter B-fragments -> registers (40 x 16B per lane, L2-resident)
    short8 F[5][8];
    #pragma unroll
    for (int ft = 0; ft < 5; ++ft)
        #pragma unroll
        for (int ks = 0; ks < 8; ++ks)
            F[ft][ks] = *reinterpret_cast<const short8*>(
                afrag + ((((ft*8+ks)*4+q)*16) + n)*8);

    // x tile -> 8 shifted bf16 copies (zero-padded outside the sequence)
    for (int c = 0; c < 8; ++c) {
        unsigned short* cp = xsh + c*XS_H;
        for (int m = tid; m < XS_LEN; m += 256) {
            int g = t0 - PAD + m + c;
            float v = (g >= 0 && g < SEQ) ? xb[g] : 0.0f;
            __hip_bfloat16 h = __float2bfloat16(v);
            cp[m] = *reinterpret_cast<unsigned short*>(&h);
        }
    }
    __syncthreads();   // once; full drain here is harmless

    // per-lane A-frag base: copy (lane&7), + 8*bit3(m) + 8*q halfwords
    const int abase = (lane & 7)*XS_H + 8*((lane >> 3) & 1) + 8*q;
    float* ob = out + (size_t)b*N_FILT*SEQ + t0;

    for (int t = 0; t < NT_STEPS; ++t) {
        const int pt = 4*t + w;            // wave's pos-tile in this stripe
        short8 A[8];
        #pragma unroll
        for (int ks = 0; ks < 8; ++ks)
            A[ks] = *reinterpret_cast<const short8*>(
                xsh + abase + pt*16 + 32*ks);

        float* buf = osh[t & 1];
        #pragma unroll
        for (int ft = 0; ft < 5; ++ft) {
            floatx4 acc = {0.f, 0.f, 0.f, 0.f};
            #pragma unroll
            for (int ks = 0; ks < 8; ++ks)
                acc = __builtin_amdgcn_mfma_f32_16x16x32_bf16(
                          A[ks], F[ft][ks], acc, 0, 0, 0);
            // D: col = lane&15 (filter), rows = 4q..4q+3 (pos) -> one float4
            // stripe offset = pt*16 - 64t + 4q = 16w + 4q
            *reinterpret_cast<floatx4*>(
                buf + (ft*16 + n)*OS_W + 16*w + 4*q) = acc;
        }
        barrier_lds_only();   // stripe complete; do NOT drain stores

        // cooperative store: 80 rows x 64 pos; wave instr = 4 x 256 B runs
        const float* rbuf = osh[t & 1];
        #pragma unroll
        for (int it = 0; it < 5; ++it) {
            int idx = it*256 + tid;
            int f   = idx >> 4;            // filter row 0..79
            int c4  = idx & 15;            // float4 within stripe row
            floatx4 v = *reinterpret_cast<const floatx4*>(
                rbuf + f*OS_W + 4*c4);
            *reinterpret_cast<floatx4*>(
                ob + (size_t)f*SEQ + 64*t + 4*c4) = v;
        }
        // buffer reuse safety: write(t+2) to this buffer happens after
        // barrier(t+1), by which time every wave's read(t) is lgkm-complete.
    }
}

extern "C" void kernel_launch(void* const* d_in, const int* in_sizes, int n_in,
                              void* d_out, int out_size, void* d_ws, size_t ws_size,
                              hipStream_t stream) {
    const float* x    = (const float*)d_in[0];
    const float* b1   = (const float*)d_in[1];
    const float* band = (const float*)d_in[2];
    unsigned short* afrag = (unsigned short*)d_ws;   // 80*256*2 = 40960 B
    float* out = (float*)d_out;

    gen_filters<<<N_FILT, 256, 0, stream>>>(b1, band, afrag);

    dim3 grid(SEQ / BLK_POS, BATCH);                 // 25 x 32 = 800 blocks
    conv_mfma<<<grid, 256, 0, stream>>>(x, afrag, out);
}

// Round 4
// 354.686 us; speedup vs baseline: 1.0667x; 1.0094x over previous
//
#include <hip/hip_runtime.h>
#include <hip/hip_bf16.h>

#define N_FILT   80
#define FILT_DIM 251
#define PAD      125
#define SEQ      32000
#define BATCH    32
#define TWO_PI_F 6.28318530717958647692f

typedef __attribute__((ext_vector_type(8))) short short8;
typedef __attribute__((ext_vector_type(4))) float floatx4;

// ---------------- Kernel 1: filters -> bf16 fragments (UNCHANGED) ----------
// Fragment order works for BOTH operand roles: lane&15 indexes the non-K dim,
// (lane>>4)*8+j indexes K.  half-index: (((ft*8+ks)*4+q)*16 + m)*8 + j,
// f = 16*ft + m, tap k = 32*ks + 8*q + j.  K padded 251->256 with zeros.
__global__ void gen_filters(const float* __restrict__ b1p,
                            const float* __restrict__ bandp,
                            unsigned short* __restrict__ afrag) {
    const int f = blockIdx.x;      // filter 0..79
    const int i = threadIdx.x;     // tap 0..255

    const float min_f = 0.003125f; // 50/16000 exact
    float b1   = fabsf(b1p[f]);
    float band = fabsf(bandp[f]);
    float beg  = b1 + min_f;
    float end  = beg + band + min_f;

    float bp = -1e30f;
    if (i < FILT_DIM) {
        int d = i - PAD;
        float lpe, lpb;
        if (d == 0) { lpe = 2.0f*end; lpb = 2.0f*beg; }
        else {
            float kf = (float)(d < 0 ? -d : d);
            float ae = (TWO_PI_F * (end * 16000.0f)) * kf;
            float ab = (TWO_PI_F * (beg * 16000.0f)) * kf;
            lpe = (2.0f*end) * (sinf(ae)/ae);
            lpb = (2.0f*beg) * (sinf(ab)/ab);
        }
        bp = lpe - lpb;
    }

    __shared__ float red[256];
    red[i] = bp;
    __syncthreads();
    for (int s = 128; s > 0; s >>= 1) {
        if (i < s) red[i] = fmaxf(red[i], red[i+s]);
        __syncthreads();
    }
    float mx = red[0];

    float val = 0.0f;
    if (i < FILT_DIM) {
        float n = (float)i * (251.0f/250.0f);
        float w = 0.54f - 0.46f*cosf((TWO_PI_F*n)/251.0f);
        val = (bp/mx) * w;
    }
    __hip_bfloat16 h = __float2bfloat16(val);
    const int ft = f >> 4, m = f & 15;
    const int ks = i >> 5, q = (i >> 3) & 3, j = i & 7;
    afrag[((((ft*8+ks)*4+q)*16) + m)*8 + j] = *reinterpret_cast<unsigned short*>(&h);
}

// ---------------- Kernel 2: implicit-GEMM conv, transposed epilogue --------
// A = x (rows = positions), B = filters (regs).  pt = 4t + w so each t-step
// the 4 waves jointly produce a contiguous 64-pos x 80-filt stripe, which is
// transposed through double-buffered LDS and stored block-cooperatively.
//
// KEY CHANGE (r4): NONTEMPORAL output stores.  Evidence: three store-issue-
// side fixes (fewer/wider store instrs, 256B contiguous runs, no vmcnt drain
// at barriers) were all ~null, yet conv runs ~130us vs a ~55us write floor.
// Theory: cached stores write-allocate through L2 *and* L3; every L3
// allocation first evicts a dirty poison line from the harness's 1.31GB
// pre-fill (L3 is dirty-full at conv start), so the HBM-facing stream is
// randomized poison evictions regardless of our store shape, and each output
// byte transits the hierarchy 3x.  global_store nt does a coherent lookup
// (dirty-hit updates in place -> readback-safe) but does NOT allocate on
// miss: the write passes straight to HBM, un-laundered and un-amplified.
#define BLK_POS  1280
#define NT_STEPS 20            // t-steps, 4 pos-tiles (waves) per step
#define XS_LEN   1528          // staged halfwords per copy
#define XS_H     1544          // stride: 772 dw == 4 (mod 32) -> bank phase
#define OS_W     72            // stripe row stride (floats): 8f-mod-32 phase

__device__ __forceinline__ void barrier_lds_only() {
    asm volatile("s_waitcnt lgkmcnt(0)" ::: "memory");
    __builtin_amdgcn_s_barrier();
}

__global__ __launch_bounds__(256, 2) void conv_mfma(
        const float* __restrict__ x,
        const unsigned short* __restrict__ afrag,
        float* __restrict__ out) {
    __shared__ __align__(16) unsigned short xsh[8*XS_H];        // 24704 B
    __shared__ __align__(16) float osh[2][N_FILT*OS_W];         // 46080 B

    const int b    = blockIdx.y;
    const int t0   = blockIdx.x * BLK_POS;
    const int tid  = threadIdx.x;
    const int lane = tid & 63;
    const int w    = tid >> 6;
    const int n    = lane & 15;    // MFMA col = filter within ftile
    const int q    = lane >> 4;    // quad -> k-base 8q, D-rows 4q..4q+3
    const float* xb = x + (size_t)b * SEQ;

    // filter B-fragments -> registers (40 x 16B per lane, L2-resident)
    short8 F[5][8];
    #pragma unroll
    for (int ft = 0; ft < 5; ++ft)
        #pragma unroll
        for (int ks = 0; ks < 8; ++ks)
            F[ft][ks] = *reinterpret_cast<const short8*>(
                afrag + ((((ft*8+ks)*4+q)*16) + n)*8);

    // x tile -> 8 shifted bf16 copies (zero-padded outside the sequence)
    for (int c = 0; c < 8; ++c) {
        unsigned short* cp = xsh + c*XS_H;
        for (int m = tid; m < XS_LEN; m += 256) {
            int g = t0 - PAD + m + c;
            float v = (g >= 0 && g < SEQ) ? xb[g] : 0.0f;
            __hip_bfloat16 h = __float2bfloat16(v);
            cp[m] = *reinterpret_cast<unsigned short*>(&h);
        }
    }
    __syncthreads();   // once; full drain here is harmless

    // per-lane A-frag base: copy (lane&7), + 8*bit3(m) + 8*q halfwords
    const int abase = (lane & 7)*XS_H + 8*((lane >> 3) & 1) + 8*q;
    float* ob = out + (size_t)b*N_FILT*SEQ + t0;

    for (int t = 0; t < NT_STEPS; ++t) {
        const int pt = 4*t + w;            // wave's pos-tile in this stripe
        short8 A[8];
        #pragma unroll
        for (int ks = 0; ks < 8; ++ks)
            A[ks] = *reinterpret_cast<const short8*>(
                xsh + abase + pt*16 + 32*ks);

        float* buf = osh[t & 1];
        #pragma unroll
        for (int ft = 0; ft < 5; ++ft) {
            floatx4 acc = {0.f, 0.f, 0.f, 0.f};
            #pragma unroll
            for (int ks = 0; ks < 8; ++ks)
                acc = __builtin_amdgcn_mfma_f32_16x16x32_bf16(
                          A[ks], F[ft][ks], acc, 0, 0, 0);
            // D: col = lane&15 (filter), rows = 4q..4q+3 (pos) -> one float4
            // stripe offset = pt*16 - 64t + 4q = 16w + 4q
            *reinterpret_cast<floatx4*>(
                buf + (ft*16 + n)*OS_W + 16*w + 4*q) = acc;
        }
        barrier_lds_only();   // stripe complete; do NOT drain stores

        // cooperative store: 80 rows x 64 pos; wave instr = 4 x 256 B runs,
        // issued NONTEMPORAL (no L2/L3 allocate -> straight to HBM)
        const float* rbuf = osh[t & 1];
        #pragma unroll
        for (int it = 0; it < 5; ++it) {
            int idx = it*256 + tid;
            int f   = idx >> 4;            // filter row 0..79
            int c4  = idx & 15;            // float4 within stripe row
            floatx4 v = *reinterpret_cast<const floatx4*>(
                rbuf + f*OS_W + 4*c4);
            __builtin_nontemporal_store(v,
                reinterpret_cast<floatx4*>(
                    ob + (size_t)f*SEQ + 64*t + 4*c4));
        }
        // buffer reuse safety: write(t+2) to this buffer happens after
        // barrier(t+1), by which time every wave's read(t) is lgkm-complete.
    }
}

extern "C" void kernel_launch(void* const* d_in, const int* in_sizes, int n_in,
                              void* d_out, int out_size, void* d_ws, size_t ws_size,
                              hipStream_t stream) {
    const float* x    = (const float*)d_in[0];
    const float* b1   = (const float*)d_in[1];
    const float* band = (const float*)d_in[2];
    unsigned short* afrag = (unsigned short*)d_ws;   // 80*256*2 = 40960 B
    float* out = (float*)d_out;

    gen_filters<<<N_FILT, 256, 0, stream>>>(b1, band, afrag);

    dim3 grid(SEQ / BLK_POS, BATCH);                 // 25 x 32 = 800 blocks
    conv_mfma<<<grid, 256, 0, stream>>>(x, afrag, out);
}